// Round 8
// baseline (2669.862 us; speedup 1.0000x reference)
//
#include <hip/hip_runtime.h>

typedef unsigned short u16;
typedef unsigned int u32;
typedef __attribute__((ext_vector_type(4))) float f32x4;
typedef __attribute__((ext_vector_type(8))) short s16x8;
typedef __attribute__((ext_vector_type(4))) int i32x4;

#define EPS 1e-5f

// ---------- helpers ----------
__device__ __forceinline__ u16 f2bf(float f) {
  unsigned u = __float_as_uint(f);
  return (u16)((u + 0x7fffu + ((u >> 16) & 1u)) >> 16);
}
__device__ __forceinline__ float sigm(float x) { return 1.0f / (1.0f + __expf(-x)); }
__device__ __forceinline__ float tanh_f(float x) {
  float e = __expf(-2.0f * fabsf(x));
  float r = (1.0f - e) / (1.0f + e);
  return copysignf(r, x);
}
__device__ __forceinline__ void gl_lds16(const void* g, void* l) {
  __builtin_amdgcn_global_load_lds(
      (const __attribute__((address_space(1))) u32*)g,
      (__attribute__((address_space(3))) u32*)l, 16, 0, 0);
}

// ---------- weight pack: conv_w (512,192,5) f32 -> per-fragment bf16 ----------
// f = (tap*6+kk)*32 + of ; of = gate-ch>>4 ; element = lane*8+j
// A[o][c]: o = of*16 + (lane&15), c = kk*32 + (lane>>4)*8 + j
__global__ __launch_bounds__(256) void k_wcvt(const float* __restrict__ w, u16* __restrict__ Wpk) {
  int idx = blockIdx.x * 256 + threadIdx.x;   // exactly 491520 threads
  int f = idx >> 9, r = idx & 511;
  int lane = r >> 3, j = r & 7;
  int of = f & 31, tk = f >> 5;
  int kk = tk % 6, tap = tk / 6;
  int o = (of << 4) + (lane & 15);
  int c = (kk << 5) + ((lane >> 4) << 3) + j;
  Wpk[idx] = f2bf(w[(o * 192 + c) * 5 + tap]);
}

// ---------- x transpose: inputs (t,b,64,256) f32 -> xT[t*32+b][264 rows][64 c] bf16, swizzled ----------
__global__ __launch_bounds__(256) void k_xtrans(const float* __restrict__ x, u16* __restrict__ xT) {
  int tb = blockIdx.x;
  int tid = threadIdx.x;
  __shared__ __align__(16) u16 ltile[256 * 72];
  const float* src = x + tb * (64 * 256);
  for (int it = 0; it < 64; ++it) {
    int idx = it * 256 + tid;
    int c = idx >> 8, l = idx & 255;
    ltile[l * 72 + c] = f2bf(src[idx]);
  }
  __syncthreads();
  char* dst = (char*)(xT + tb * 16896);   // 264*64 u16 = 33792 B
  i32x4 z = {0, 0, 0, 0};
  for (int i = tid; i < 2112; i += 256) { // 264 rows * 8 chunks
    int r = i >> 3, ch = i & 7;
    i32x4 v = z;
    if (r >= 2 && r < 258) v = *(const i32x4*)(ltile + (r - 2) * 72 + ch * 8);
    *(i32x4*)(dst + r * 128 + ((ch * 16) ^ ((r & 7) << 4))) = v;
  }
}

// ---------- zero cx buffer 0 ----------
__global__ void k_init(i32x4* __restrict__ cx0) {
  int n = gridDim.x * blockDim.x;
  int tid = blockIdx.x * blockDim.x + threadIdx.x;
  i32x4 z = {0, 0, 0, 0};
  for (int i = tid; i < 262144; i += n) cx0[i] = z;   // 32*128*256 f32
}

// ---------- fused step t: pointwise(t-1) -> h(t) in LDS -> conv -> gates(t)+stats(t) ----------
// grid 256: bid = ((g*2+lh)<<5) + b  (b -> XCD b%8); block 512 = 8 waves (wm2 x wl4)
// Block: gate g (128 gate-ch) x 128 L (lh); wave 64ch x 32L.
// Ping-pong: reads gates/stats/cx buf[(t&1)^1], writes buf[t&1]. No cross-block deps.
__global__ __launch_bounds__(512, 2) void k_step(
    const u16* __restrict__ Wpk, const u16* __restrict__ xT,
    const float* __restrict__ cb, const float* __restrict__ gnw, const float* __restrict__ gnb,
    float* __restrict__ gates, float* __restrict__ stats, float* __restrict__ cxb,
    float* __restrict__ out, int t) {
  const int bid = blockIdx.x;
  const int b = bid & 31, lh = (bid >> 5) & 1, g = bid >> 6;
  const int L0 = lh << 7;
  const int tid = threadIdx.x, wave = tid >> 6, lane = tid & 63;
  const int wm = wave & 1, wl = wave >> 1;
  const int cgrp = (lane >> 4) << 4;
  const int l15 = lane & 15;

  __shared__ __align__(16) char ldsx[16896];   // 132 rows x 128 B (x, swizzled)
  __shared__ __align__(16) char ldsh[33792];   // 132 rows x 256 B (h bf16, swizzled)
  __shared__ float red[8][2][2];
  __shared__ float smu[16], srs[16];

  const int cur = t & 1, prv = cur ^ 1;
  const float* gprev = gates + prv * 4194304 + (b << 17);   // [b][512][256]
  float*       gcur  = gates + cur * 4194304 + (b << 17);
  const float* cxp   = cxb + prv * 1048576 + (b << 15);     // [b][128][256]
  float*       cxc   = cxb + cur * 1048576 + (b << 15);

  // ---- issue x(t) staging (async) ----
  {
    const char* gx = (const char*)(xT + ((t << 5) + b) * 16896) + (lh << 14);
    for (int i = tid; i < 1056; i += 512) gl_lds16(gx + (i << 4), ldsx + (i << 4));
  }

  // ---- pointwise of step t-1 (redundant across g; only g==0 writes out/cx) ----
  if (t > 0) {
    if (tid < 16) {
      const float* sp = stats + (prv << 11);
      float s = sp[((b << 1) << 5) + (tid << 1)] + sp[(((b << 1) | 1) << 5) + (tid << 1)];
      float q = sp[((b << 1) << 5) + (tid << 1) + 1] + sp[(((b << 1) | 1) << 5) + (tid << 1) + 1];
      const float inv = 1.0f / 8192.0f;
      float m = s * inv;
      smu[tid] = m;
      srs[tid] = rsqrtf(q * inv - m * m + EPS);
    }
    __syncthreads();
    const int o = tid & 15, lq = tid >> 4;
    const int cs = o >> 2;
    const float mu0 = smu[cs],      rsv0 = srs[cs];
    const float mu1 = smu[4 + cs],  rsv1 = srs[4 + cs];
    const float mu2 = smu[8 + cs],  rsv2 = srs[8 + cs];
    const float mu3 = smu[12 + cs], rsv3 = srs[12 + cs];
    float* outp = out + ((((t - 1) << 5) + b) << 15);
    #pragma unroll
    for (int i = 0; i < 4; ++i) {
      const int lrel = lq + (i << 5);
      const int l = L0 + lrel;
      const int row = lrel + 2;
      u16 hp[8];
      #pragma unroll
      for (int r = 0; r < 8; ++r) {
        const int c = (o << 3) + r;
        float vi = gprev[((c      ) << 8) + l];
        float vf = gprev[((c + 128) << 8) + l];
        float vg = gprev[((c + 256) << 8) + l];
        float vo = gprev[((c + 384) << 8) + l];
        vi = (vi - mu0) * rsv0 * gnw[c]       + gnb[c];
        vf = (vf - mu1) * rsv1 * gnw[c + 128] + gnb[c + 128];
        vg = (vg - mu2) * rsv2 * gnw[c + 256] + gnb[c + 256];
        vo = (vo - mu3) * rsv3 * gnw[c + 384] + gnb[c + 384];
        const int ci = (c << 8) + l;
        float cyv = sigm(vf) * cxp[ci] + sigm(vi) * tanh_f(vg);
        float hyv = sigm(vo) * tanh_f(cyv);
        hp[r] = f2bf(hyv);
        if (g == 0) { cxc[ci] = cyv; outp[ci] = hyv; }
      }
      *(i32x4*)(ldsh + (row << 8) + ((o ^ (row & 7)) << 4)) = *(const i32x4*)hp;
    }
    // halo rows 0,1,130,131 (l = L0-2,-1,+128,+129): compute h only (no out/cx)
    if (tid < 64) {
      const int hr = tid >> 4;                 // o = tid&15 == main o
      const int lrel = (hr < 2) ? (hr - 2) : (126 + hr);
      const int l = L0 + lrel, row = lrel + 2;
      u16 hp[8];
      if (l >= 0 && l < 256) {
        #pragma unroll
        for (int r = 0; r < 8; ++r) {
          const int c = (o << 3) + r;
          float vi = gprev[((c      ) << 8) + l];
          float vf = gprev[((c + 128) << 8) + l];
          float vg = gprev[((c + 256) << 8) + l];
          float vo = gprev[((c + 384) << 8) + l];
          vi = (vi - mu0) * rsv0 * gnw[c]       + gnb[c];
          vf = (vf - mu1) * rsv1 * gnw[c + 128] + gnb[c + 128];
          vg = (vg - mu2) * rsv2 * gnw[c + 256] + gnb[c + 256];
          vo = (vo - mu3) * rsv3 * gnw[c + 384] + gnb[c + 384];
          const int ci = (c << 8) + l;
          float cyv = sigm(vf) * cxp[ci] + sigm(vi) * tanh_f(vg);
          float hyv = sigm(vo) * tanh_f(cyv);
          hp[r] = f2bf(hyv);
        }
      } else {
        #pragma unroll
        for (int r = 0; r < 8; ++r) hp[r] = 0;
      }
      *(i32x4*)(ldsh + (row << 8) + ((o ^ (row & 7)) << 4)) = *(const i32x4*)hp;
    }
  } else {
    i32x4 z = {0, 0, 0, 0};
    for (int i = tid; i < 2112; i += 512) *((i32x4*)ldsh + i) = z;
  }
  asm volatile("s_waitcnt vmcnt(0) lgkmcnt(0)" ::: "memory");
  __syncthreads();

  // ---- K-loop: 30 chunks, A direct from L1/L2, B from LDS, no barriers ----
  f32x4 zero4 = {0.f, 0.f, 0.f, 0.f};
  f32x4 acc[4][2];
  #pragma unroll
  for (int mi = 0; mi < 4; ++mi) { acc[mi][0] = zero4; acc[mi][1] = zero4; }

  const s16x8* Wv = (const s16x8*)Wpk;
  const int afb = (g << 3) + (wm << 2);
  for (int tap = 0; tap < 5; ++tap) {
    #pragma unroll
    for (int kk = 0; kk < 6; ++kk) {
      const int cc = tap * 6 + kk;
      s16x8 av[4], bv[2];
      #pragma unroll
      for (int mi = 0; mi < 4; ++mi)
        av[mi] = Wv[(((cc << 5) + afb + mi) << 6) + lane];
      #pragma unroll
      for (int ni = 0; ni < 2; ++ni) {
        const int row = (wl << 5) + (ni << 4) + l15 + tap;
        const int sw = (row & 7) << 4;
        bv[ni] = (kk < 2)
          ? *(const s16x8*)(ldsx + (row << 7) + (((kk << 6) + cgrp) ^ sw))
          : *(const s16x8*)(ldsh + (row << 8) + ((((kk - 2) << 6) + cgrp) ^ sw));
      }
      #pragma unroll
      for (int mi = 0; mi < 4; ++mi) {
        acc[mi][0] = __builtin_amdgcn_mfma_f32_16x16x32_bf16(av[mi], bv[0], acc[mi][0], 0, 0, 0);
        acc[mi][1] = __builtin_amdgcn_mfma_f32_16x16x32_bf16(av[mi], bv[1], acc[mi][1], 0, 0, 0);
      }
    }
  }

  // ---- epilogue: +bias, write f32 gates(t), per-group partial stats ----
  const int ch4 = (lane >> 4) << 2;
  float sum[2] = {0.f, 0.f}, sq[2] = {0.f, 0.f};
  #pragma unroll
  for (int mi = 0; mi < 4; ++mi) {
    const int gc0 = (g << 7) + (wm << 6) + (mi << 4) + ch4;
    const f32x4 bias = *(const f32x4*)(cb + gc0);
    const int gi = mi >> 1;
    #pragma unroll
    for (int ni = 0; ni < 2; ++ni) {
      const int l = L0 + (wl << 5) + (ni << 4) + l15;
      #pragma unroll
      for (int r = 0; r < 4; ++r) {
        float v = acc[mi][ni][r] + bias[r];
        gcur[((gc0 + r) << 8) + l] = v;
        sum[gi] += v; sq[gi] += v * v;
      }
    }
  }
  #pragma unroll
  for (int off = 1; off < 64; off <<= 1) {
    sum[0] += __shfl_xor(sum[0], off); sq[0] += __shfl_xor(sq[0], off);
    sum[1] += __shfl_xor(sum[1], off); sq[1] += __shfl_xor(sq[1], off);
  }
  if (lane == 0) {
    red[wave][0][0] = sum[0]; red[wave][0][1] = sq[0];
    red[wave][1][0] = sum[1]; red[wave][1][1] = sq[1];
  }
  __syncthreads();
  if (tid < 8) {   // fixed-order 4-wave sum -> deterministic, no atomics
    const int cs2 = tid >> 1, j = tid & 1;
    const int wm2 = cs2 >> 1, gi = cs2 & 1;
    float v = red[wm2][gi][j] + red[wm2 + 2][gi][j] + red[wm2 + 4][gi][j] + red[wm2 + 6][gi][j];
    stats[(cur << 11) + (((b << 1) | lh) << 5) + (((g << 2) + cs2) << 1) + j] = v;
  }
}

// ---------- final pointwise (step 31): out(31) + hy + cy ----------
// grid 256 = s(8) x b(32); block 256
__global__ __launch_bounds__(256) void k_final(
    const float* __restrict__ gates1, const float* __restrict__ stats1,
    const float* __restrict__ cx1, const float* __restrict__ gnw, const float* __restrict__ gnb,
    float* __restrict__ out) {
  const int bid = blockIdx.x;
  const int b = bid & 31, s = bid >> 5;
  const int tid = threadIdx.x;
  const int o = (s << 1) | (tid >> 7), lb = tid & 127;
  const int cs = o >> 2;
  const float inv = 1.0f / 8192.0f;
  const float* gp = gates1 + (b << 17);   // [b][512][256]
  const float* cp = cx1 + (b << 15);      // [b][128][256]
  float mu[4], rs[4];
  #pragma unroll
  for (int gg = 0; gg < 4; ++gg) {
    const int grp = (gg << 2) + cs;
    float sv = stats1[((b << 1) << 5) + (grp << 1)] + stats1[(((b << 1) | 1) << 5) + (grp << 1)];
    float qv = stats1[((b << 1) << 5) + (grp << 1) + 1] + stats1[(((b << 1) | 1) << 5) + (grp << 1) + 1];
    float m = sv * inv;
    mu[gg] = m;
    rs[gg] = rsqrtf(qv * inv - m * m + EPS);
  }
  float* outp = out + (((31 << 5) + b) << 15);
  #pragma unroll
  for (int half = 0; half < 2; ++half) {
    const int l = (half << 7) + lb;
    #pragma unroll
    for (int r = 0; r < 8; ++r) {
      const int c = (o << 3) + r;
      float vi = gp[((c      ) << 8) + l];
      float vf = gp[((c + 128) << 8) + l];
      float vg = gp[((c + 256) << 8) + l];
      float vo = gp[((c + 384) << 8) + l];
      vi = (vi - mu[0]) * rs[0] * gnw[c]       + gnb[c];
      vf = (vf - mu[1]) * rs[1] * gnw[c + 128] + gnb[c + 128];
      vg = (vg - mu[2]) * rs[2] * gnw[c + 256] + gnb[c + 256];
      vo = (vo - mu[3]) * rs[3] * gnw[c + 384] + gnb[c + 384];
      const int ci = (c << 8) + l;
      float cyv = sigm(vf) * cp[ci] + sigm(vi) * tanh_f(vg);
      float hyv = sigm(vo) * tanh_f(cyv);
      outp[ci] = hyv;
      const int cxi = (((b << 7) + c) << 8) + l;
      out[33554432 + cxi] = hyv;   // final hy
      out[34603008 + cxi] = cyv;   // final cy
    }
  }
}

// ---------- launch ----------
extern "C" void kernel_launch(void* const* d_in, const int* in_sizes, int n_in,
                              void* d_out, int out_size, void* d_ws, size_t ws_size,
                              hipStream_t stream) {
  const float* x  = (const float*)d_in[0];
  const float* cw = (const float*)d_in[1];
  const float* cb = (const float*)d_in[2];
  const float* gw = (const float*)d_in[3];
  const float* gb = (const float*)d_in[4];
  float* out = (float*)d_out;
  char* ws = (char*)d_ws;

  u16*   Wpk   = (u16*)(ws);                 //     983,040 B
  u16*   xT    = (u16*)(ws + 983040);        //  34,603,008 B
  float* gates = (float*)(ws + 35586048);    //  33,554,432 B (2 bufs)
  float* cxb   = (float*)(ws + 69140480);    //   8,388,608 B (2 bufs)
  float* stats = (float*)(ws + 77529088);    //      16,384 B (2 bufs) (~77.5 MB)

  k_wcvt<<<1920, 256, 0, stream>>>(cw, Wpk);
  k_xtrans<<<1024, 256, 0, stream>>>(x, xT);
  k_init<<<256, 256, 0, stream>>>((i32x4*)cxb);
  for (int t = 0; t < 32; ++t)
    k_step<<<256, 512, 0, stream>>>(Wpk, xT, cb, gw, gb, gates, stats, cxb, out, t);
  k_final<<<256, 256, 0, stream>>>(gates + 4194304, stats + 2048, cxb + 1048576, gw, gb, out);
}

// Round 9
// 1457.739 us; speedup vs baseline: 1.8315x; 1.8315x over previous
//
#include <hip/hip_runtime.h>

typedef unsigned short u16;
typedef unsigned int u32;
typedef __attribute__((ext_vector_type(4))) float f32x4;
typedef __attribute__((ext_vector_type(8))) short s16x8;
typedef __attribute__((ext_vector_type(4))) int i32x4;

#define EPS 1e-5f

// ---------- helpers ----------
__device__ __forceinline__ u16 f2bf(float f) {
  unsigned u = __float_as_uint(f);
  return (u16)((u + 0x7fffu + ((u >> 16) & 1u)) >> 16);
}
__device__ __forceinline__ float sigm(float x) { return 1.0f / (1.0f + __expf(-x)); }
__device__ __forceinline__ float tanh_f(float x) {
  float e = __expf(-2.0f * fabsf(x));
  float r = (1.0f - e) / (1.0f + e);
  return copysignf(r, x);
}
__device__ __forceinline__ void gl_lds16(const void* g, void* l) {
  __builtin_amdgcn_global_load_lds(
      (const __attribute__((address_space(1))) u32*)g,
      (__attribute__((address_space(3))) u32*)l, 16, 0, 0);
}

// ---------- weight pack: conv_w (512,192,5) f32 -> per-fragment bf16 ----------
// f = (tap*6+kk)*32 + of ; of = gate-ch>>4 ; element = lane*8+j
// A[o][c]: o = of*16 + (lane&15), c = kk*32 + (lane>>4)*8 + j
__global__ __launch_bounds__(256) void k_wcvt(const float* __restrict__ w, u16* __restrict__ Wpk) {
  int idx = blockIdx.x * 256 + threadIdx.x;   // exactly 491520 threads
  int f = idx >> 9, r = idx & 511;
  int lane = r >> 3, j = r & 7;
  int of = f & 31, tk = f >> 5;
  int kk = tk % 6, tap = tk / 6;
  int o = (of << 4) + (lane & 15);
  int c = (kk << 5) + ((lane >> 4) << 3) + j;
  Wpk[idx] = f2bf(w[(o * 192 + c) * 5 + tap]);
}

// ---------- x transpose: inputs (t,b,64,256) f32 -> xT[t*32+b][264 rows][64 c] bf16, swizzled ----------
__global__ __launch_bounds__(256) void k_xtrans(const float* __restrict__ x, u16* __restrict__ xT) {
  int tb = blockIdx.x;
  int tid = threadIdx.x;
  __shared__ __align__(16) u16 ltile[256 * 72];
  const float* src = x + tb * (64 * 256);
  for (int it = 0; it < 64; ++it) {
    int idx = it * 256 + tid;
    int c = idx >> 8, l = idx & 255;
    ltile[l * 72 + c] = f2bf(src[idx]);
  }
  __syncthreads();
  char* dst = (char*)(xT + tb * 16896);   // 264*64 u16 = 33792 B
  i32x4 z = {0, 0, 0, 0};
  for (int i = tid; i < 2112; i += 256) { // 264 rows * 8 chunks
    int r = i >> 3, ch = i & 7;
    i32x4 v = z;
    if (r >= 2 && r < 258) v = *(const i32x4*)(ltile + (r - 2) * 72 + ch * 8);
    *(i32x4*)(dst + r * 128 + ((ch * 16) ^ ((r & 7) << 4))) = v;
  }
}

// ---------- zero cx buffer 0 ----------
__global__ void k_init(i32x4* __restrict__ cx0) {
  int n = gridDim.x * blockDim.x;
  int tid = blockIdx.x * blockDim.x + threadIdx.x;
  i32x4 z = {0, 0, 0, 0};
  for (int i = tid; i < 262144; i += n) cx0[i] = z;   // 32*128*256 f32
}

// ---------- fused step t: pointwise(t-1) -> h(t) in LDS -> conv -> gates(t)+stats(t) ----------
// grid 256: bid = ((g*2+lh)<<5) + b  (b -> XCD b%8); block 512 = 8 waves (wm2 x wl4)
// Block: gate g (128 gate-ch) x 128 L (lh); wave 64ch x 32L.
// Ping-pong: reads gates/stats/cx buf[(t&1)^1], writes buf[t&1]. No cross-block deps.
// Pointwise is L-MAJOR: consecutive lanes -> consecutive l -> coalesced gate reads.
__global__ __launch_bounds__(512, 2) void k_step(
    const u16* __restrict__ Wpk, const u16* __restrict__ xT,
    const float* __restrict__ cb, const float* __restrict__ gnw, const float* __restrict__ gnb,
    float* __restrict__ gates, float* __restrict__ stats, float* __restrict__ cxb,
    float* __restrict__ out, int t) {
  const int bid = blockIdx.x;
  const int b = bid & 31, lh = (bid >> 5) & 1, g = bid >> 6;
  const int L0 = lh << 7;
  const int tid = threadIdx.x, wave = tid >> 6, lane = tid & 63;
  const int wm = wave & 1, wl = wave >> 1;
  const int cgrp = (lane >> 4) << 4;
  const int l15 = lane & 15;

  __shared__ __align__(16) char ldsx[16896];   // 132 rows x 128 B (x, swizzled)
  __shared__ __align__(16) char ldsh[33792];   // 132 rows x 256 B (h bf16, swizzled)
  __shared__ float red[8][2][2];
  __shared__ float smu[16], srs[16];

  const int cur = t & 1, prv = cur ^ 1;
  const float* gprev = gates + prv * 4194304 + (b << 17);   // [b][512][256]
  float*       gcur  = gates + cur * 4194304 + (b << 17);
  const float* cxp   = cxb + prv * 1048576 + (b << 15);     // [b][128][256]
  float*       cxc   = cxb + cur * 1048576 + (b << 15);

  // ---- issue x(t) staging (async) ----
  {
    const char* gx = (const char*)(xT + ((t << 5) + b) * 16896) + (lh << 14);
    for (int i = tid; i < 1056; i += 512) gl_lds16(gx + (i << 4), ldsx + (i << 4));
  }

  // ---- pointwise of step t-1 (redundant across g; only g==0 writes out/cx) ----
  if (t > 0) {
    if (tid < 16) {
      const float* sp = stats + (prv << 11);
      float s = sp[((b << 1) << 5) + (tid << 1)] + sp[(((b << 1) | 1) << 5) + (tid << 1)];
      float q = sp[((b << 1) << 5) + (tid << 1) + 1] + sp[(((b << 1) | 1) << 5) + (tid << 1) + 1];
      const float inv = 1.0f / 8192.0f;
      float m = s * inv;
      smu[tid] = m;
      srs[tid] = rsqrtf(q * inv - m * m + EPS);
    }
    __syncthreads();
    // main rows: l-major, coalesced (lq = consecutive l per lane)
    const int lq = tid & 127;
    const int oq = tid >> 7;        // wave-uniform
    const int l = L0 + lq;
    const int row = lq + 2;
    float* outp = out + ((((t - 1) << 5) + b) << 15);
    #pragma unroll
    for (int i = 0; i < 4; ++i) {
      const int o = (i << 2) + oq;  // octet 0..15, wave-uniform
      const int cs = o >> 2;
      const float mu0 = smu[cs],      rsv0 = srs[cs];
      const float mu1 = smu[4 + cs],  rsv1 = srs[4 + cs];
      const float mu2 = smu[8 + cs],  rsv2 = srs[8 + cs];
      const float mu3 = smu[12 + cs], rsv3 = srs[12 + cs];
      u16 hp[8];
      #pragma unroll
      for (int r = 0; r < 8; ++r) {
        const int c = (o << 3) + r;
        float vi = gprev[((c      ) << 8) + l];
        float vf = gprev[((c + 128) << 8) + l];
        float vg = gprev[((c + 256) << 8) + l];
        float vo = gprev[((c + 384) << 8) + l];
        vi = (vi - mu0) * rsv0 * gnw[c]       + gnb[c];
        vf = (vf - mu1) * rsv1 * gnw[c + 128] + gnb[c + 128];
        vg = (vg - mu2) * rsv2 * gnw[c + 256] + gnb[c + 256];
        vo = (vo - mu3) * rsv3 * gnw[c + 384] + gnb[c + 384];
        const int ci = (c << 8) + l;
        float cyv = sigm(vf) * cxp[ci] + sigm(vi) * tanh_f(vg);
        float hyv = sigm(vo) * tanh_f(cyv);
        hp[r] = f2bf(hyv);
        if (g == 0) { cxc[ci] = cyv; outp[ci] = hyv; }
      }
      *(i32x4*)(ldsh + (row << 8) + ((o ^ (row & 7)) << 4)) = *(const i32x4*)hp;
    }
    // halo rows 0,1,130,131 (l = L0-2,-1,+128,+129): compute h only (no out/cx)
    if (tid < 64) {
      const int ho = tid & 15, hr = tid >> 4;
      const int lrel = (hr < 2) ? (hr - 2) : (126 + hr);
      const int lx = L0 + lrel, hrow = lrel + 2;
      const int hcs = ho >> 2;
      u16 hp[8];
      if (lx >= 0 && lx < 256) {
        const float hmu0 = smu[hcs],      hrs0 = srs[hcs];
        const float hmu1 = smu[4 + hcs],  hrs1 = srs[4 + hcs];
        const float hmu2 = smu[8 + hcs],  hrs2 = srs[8 + hcs];
        const float hmu3 = smu[12 + hcs], hrs3 = srs[12 + hcs];
        #pragma unroll
        for (int r = 0; r < 8; ++r) {
          const int c = (ho << 3) + r;
          float vi = gprev[((c      ) << 8) + lx];
          float vf = gprev[((c + 128) << 8) + lx];
          float vg = gprev[((c + 256) << 8) + lx];
          float vo = gprev[((c + 384) << 8) + lx];
          vi = (vi - hmu0) * hrs0 * gnw[c]       + gnb[c];
          vf = (vf - hmu1) * hrs1 * gnw[c + 128] + gnb[c + 128];
          vg = (vg - hmu2) * hrs2 * gnw[c + 256] + gnb[c + 256];
          vo = (vo - hmu3) * hrs3 * gnw[c + 384] + gnb[c + 384];
          const int ci = (c << 8) + lx;
          float cyv = sigm(vf) * cxp[ci] + sigm(vi) * tanh_f(vg);
          float hyv = sigm(vo) * tanh_f(cyv);
          hp[r] = f2bf(hyv);
        }
      } else {
        #pragma unroll
        for (int r = 0; r < 8; ++r) hp[r] = 0;
      }
      *(i32x4*)(ldsh + (hrow << 8) + ((ho ^ (hrow & 7)) << 4)) = *(const i32x4*)hp;
    }
  } else {
    i32x4 z = {0, 0, 0, 0};
    for (int i = tid; i < 2112; i += 512) *((i32x4*)ldsh + i) = z;
  }
  asm volatile("s_waitcnt vmcnt(0) lgkmcnt(0)" ::: "memory");
  __syncthreads();

  // ---- K-loop: 30 chunks, A direct from L1/L2, B from LDS, no barriers ----
  f32x4 zero4 = {0.f, 0.f, 0.f, 0.f};
  f32x4 acc[4][2];
  #pragma unroll
  for (int mi = 0; mi < 4; ++mi) { acc[mi][0] = zero4; acc[mi][1] = zero4; }

  const s16x8* Wv = (const s16x8*)Wpk;
  const int afb = (g << 3) + (wm << 2);
  for (int tap = 0; tap < 5; ++tap) {
    #pragma unroll
    for (int kk = 0; kk < 6; ++kk) {
      const int cc = tap * 6 + kk;
      s16x8 av[4], bv[2];
      #pragma unroll
      for (int mi = 0; mi < 4; ++mi)
        av[mi] = Wv[(((cc << 5) + afb + mi) << 6) + lane];
      #pragma unroll
      for (int ni = 0; ni < 2; ++ni) {
        const int row = (wl << 5) + (ni << 4) + l15 + tap;
        const int sw = (row & 7) << 4;
        bv[ni] = (kk < 2)
          ? *(const s16x8*)(ldsx + (row << 7) + (((kk << 6) + cgrp) ^ sw))
          : *(const s16x8*)(ldsh + (row << 8) + ((((kk - 2) << 6) + cgrp) ^ sw));
      }
      #pragma unroll
      for (int mi = 0; mi < 4; ++mi) {
        acc[mi][0] = __builtin_amdgcn_mfma_f32_16x16x32_bf16(av[mi], bv[0], acc[mi][0], 0, 0, 0);
        acc[mi][1] = __builtin_amdgcn_mfma_f32_16x16x32_bf16(av[mi], bv[1], acc[mi][1], 0, 0, 0);
      }
    }
  }

  // ---- epilogue: +bias, write f32 gates(t), per-group partial stats ----
  const int ch4 = (lane >> 4) << 2;
  float sum[2] = {0.f, 0.f}, sq[2] = {0.f, 0.f};
  #pragma unroll
  for (int mi = 0; mi < 4; ++mi) {
    const int gc0 = (g << 7) + (wm << 6) + (mi << 4) + ch4;
    const f32x4 bias = *(const f32x4*)(cb + gc0);
    const int gi = mi >> 1;
    #pragma unroll
    for (int ni = 0; ni < 2; ++ni) {
      const int l = L0 + (wl << 5) + (ni << 4) + l15;
      #pragma unroll
      for (int r = 0; r < 4; ++r) {
        float v = acc[mi][ni][r] + bias[r];
        gcur[((gc0 + r) << 8) + l] = v;
        sum[gi] += v; sq[gi] += v * v;
      }
    }
  }
  #pragma unroll
  for (int off = 1; off < 64; off <<= 1) {
    sum[0] += __shfl_xor(sum[0], off); sq[0] += __shfl_xor(sq[0], off);
    sum[1] += __shfl_xor(sum[1], off); sq[1] += __shfl_xor(sq[1], off);
  }
  if (lane == 0) {
    red[wave][0][0] = sum[0]; red[wave][0][1] = sq[0];
    red[wave][1][0] = sum[1]; red[wave][1][1] = sq[1];
  }
  __syncthreads();
  if (tid < 8) {   // fixed-order 4-wave sum -> deterministic, no atomics
    const int cs2 = tid >> 1, j = tid & 1;
    const int wm2 = cs2 >> 1, gi = cs2 & 1;
    float v = red[wm2][gi][j] + red[wm2 + 2][gi][j] + red[wm2 + 4][gi][j] + red[wm2 + 6][gi][j];
    stats[(cur << 11) + (((b << 1) | lh) << 5) + (((g << 2) + cs2) << 1) + j] = v;
  }
}

// ---------- final pointwise (step 31): out(31) + hy + cy ----------
// grid 256 = s(8) x b(32); block 256
__global__ __launch_bounds__(256) void k_final(
    const float* __restrict__ gates1, const float* __restrict__ stats1,
    const float* __restrict__ cx1, const float* __restrict__ gnw, const float* __restrict__ gnb,
    float* __restrict__ out) {
  const int bid = blockIdx.x;
  const int b = bid & 31, s = bid >> 5;
  const int tid = threadIdx.x;
  const int o = (s << 1) | (tid >> 7), lb = tid & 127;
  const int cs = o >> 2;
  const float inv = 1.0f / 8192.0f;
  const float* gp = gates1 + (b << 17);   // [b][512][256]
  const float* cp = cx1 + (b << 15);      // [b][128][256]
  float mu[4], rs[4];
  #pragma unroll
  for (int gg = 0; gg < 4; ++gg) {
    const int grp = (gg << 2) + cs;
    float sv = stats1[((b << 1) << 5) + (grp << 1)] + stats1[(((b << 1) | 1) << 5) + (grp << 1)];
    float qv = stats1[((b << 1) << 5) + (grp << 1) + 1] + stats1[(((b << 1) | 1) << 5) + (grp << 1) + 1];
    float m = sv * inv;
    mu[gg] = m;
    rs[gg] = rsqrtf(qv * inv - m * m + EPS);
  }
  float* outp = out + (((31 << 5) + b) << 15);
  #pragma unroll
  for (int half = 0; half < 2; ++half) {
    const int l = (half << 7) + lb;
    #pragma unroll
    for (int r = 0; r < 8; ++r) {
      const int c = (o << 3) + r;
      float vi = gp[((c      ) << 8) + l];
      float vf = gp[((c + 128) << 8) + l];
      float vg = gp[((c + 256) << 8) + l];
      float vo = gp[((c + 384) << 8) + l];
      vi = (vi - mu[0]) * rs[0] * gnw[c]       + gnb[c];
      vf = (vf - mu[1]) * rs[1] * gnw[c + 128] + gnb[c + 128];
      vg = (vg - mu[2]) * rs[2] * gnw[c + 256] + gnb[c + 256];
      vo = (vo - mu[3]) * rs[3] * gnw[c + 384] + gnb[c + 384];
      const int ci = (c << 8) + l;
      float cyv = sigm(vf) * cp[ci] + sigm(vi) * tanh_f(vg);
      float hyv = sigm(vo) * tanh_f(cyv);
      outp[ci] = hyv;
      const int cxi = (((b << 7) + c) << 8) + l;
      out[33554432 + cxi] = hyv;   // final hy
      out[34603008 + cxi] = cyv;   // final cy
    }
  }
}

// ---------- launch ----------
extern "C" void kernel_launch(void* const* d_in, const int* in_sizes, int n_in,
                              void* d_out, int out_size, void* d_ws, size_t ws_size,
                              hipStream_t stream) {
  const float* x  = (const float*)d_in[0];
  const float* cw = (const float*)d_in[1];
  const float* cb = (const float*)d_in[2];
  const float* gw = (const float*)d_in[3];
  const float* gb = (const float*)d_in[4];
  float* out = (float*)d_out;
  char* ws = (char*)d_ws;

  u16*   Wpk   = (u16*)(ws);                 //     983,040 B
  u16*   xT    = (u16*)(ws + 983040);        //  34,603,008 B
  float* gates = (float*)(ws + 35586048);    //  33,554,432 B (2 bufs)
  float* cxb   = (float*)(ws + 69140480);    //   8,388,608 B (2 bufs)
  float* stats = (float*)(ws + 77529088);    //      16,384 B (2 bufs) (~77.5 MB)

  k_wcvt<<<1920, 256, 0, stream>>>(cw, Wpk);
  k_xtrans<<<1024, 256, 0, stream>>>(x, xT);
  k_init<<<256, 256, 0, stream>>>((i32x4*)cxb);
  for (int t = 0; t < 32; ++t)
    k_step<<<256, 512, 0, stream>>>(Wpk, xT, cb, gw, gb, gates, stats, cxb, out, t);
  k_final<<<256, 256, 0, stream>>>(gates + 4194304, stats + 2048, cxb + 1048576, gw, gb, out);
}

// Round 10
// 943.033 us; speedup vs baseline: 2.8311x; 1.5458x over previous
//
#include <hip/hip_runtime.h>

typedef unsigned short u16;
typedef unsigned int u32;
typedef __attribute__((ext_vector_type(4))) float f32x4;
typedef __attribute__((ext_vector_type(8))) short s16x8;
typedef __attribute__((ext_vector_type(4))) int i32x4;

#define EPS 1e-5f

// ---------- helpers ----------
__device__ __forceinline__ u16 f2bf(float f) {
  unsigned u = __float_as_uint(f);
  return (u16)((u + 0x7fffu + ((u >> 16) & 1u)) >> 16);
}
__device__ __forceinline__ float sigm(float x) { return 1.0f / (1.0f + __expf(-x)); }
__device__ __forceinline__ float tanh_f(float x) {
  float e = __expf(-2.0f * fabsf(x));
  float r = (1.0f - e) / (1.0f + e);
  return copysignf(r, x);
}
__device__ __forceinline__ void gl_lds16(const void* g, void* l) {
  __builtin_amdgcn_global_load_lds(
      (const __attribute__((address_space(1))) u32*)g,
      (__attribute__((address_space(3))) u32*)l, 16, 0, 0);
}

// ---------- weight pack: conv_w (512,192,5) f32 -> per-fragment bf16 ----------
// f = (tap*6+kk)*32 + of ; of = gate-ch>>4 ; element = lane*8+j
// A[o][c]: o = of*16 + (lane&15), c = kk*32 + (lane>>4)*8 + j
__global__ __launch_bounds__(256) void k_wcvt(const float* __restrict__ w, u16* __restrict__ Wpk) {
  int idx = blockIdx.x * 256 + threadIdx.x;   // exactly 491520 threads
  int f = idx >> 9, r = idx & 511;
  int lane = r >> 3, j = r & 7;
  int of = f & 31, tk = f >> 5;
  int kk = tk % 6, tap = tk / 6;
  int o = (of << 4) + (lane & 15);
  int c = (kk << 5) + ((lane >> 4) << 3) + j;
  Wpk[idx] = f2bf(w[(o * 192 + c) * 5 + tap]);
}

// ---------- x transpose: inputs (t,b,64,256) f32 -> xT[t*32+b][264 rows][64 c] bf16, swizzled ----------
__global__ __launch_bounds__(256) void k_xtrans(const float* __restrict__ x, u16* __restrict__ xT) {
  int tb = blockIdx.x;
  int tid = threadIdx.x;
  __shared__ __align__(16) u16 ltile[256 * 72];
  const float* src = x + tb * (64 * 256);
  for (int it = 0; it < 64; ++it) {
    int idx = it * 256 + tid;
    int c = idx >> 8, l = idx & 255;
    ltile[l * 72 + c] = f2bf(src[idx]);
  }
  __syncthreads();
  char* dst = (char*)(xT + tb * 16896);   // 264*64 u16 = 33792 B
  i32x4 z = {0, 0, 0, 0};
  for (int i = tid; i < 2112; i += 256) { // 264 rows * 8 chunks
    int r = i >> 3, ch = i & 7;
    i32x4 v = z;
    if (r >= 2 && r < 258) v = *(const i32x4*)(ltile + (r - 2) * 72 + ch * 8);
    *(i32x4*)(dst + r * 128 + ((ch * 16) ^ ((r & 7) << 4))) = v;
  }
}

// ---------- zero h-state + c-state ----------
__global__ void k_init(i32x4* __restrict__ hT, i32x4* __restrict__ cxv) {
  int n = gridDim.x * blockDim.x;
  int tid = blockIdx.x * blockDim.x + threadIdx.x;
  i32x4 z = {0, 0, 0, 0};
  for (int i = tid; i < 135168; i += n) hT[i] = z;   // 32*264*128 u16
  for (int i = tid; i < 262144; i += n) cxv[i] = z;  // 32*128*256 f32
}

// ---------- conv + bias + gates(t) f32 + GN partial stats ----------
// grid 256: bid = ((g*2+lh)<<5) + b  (low bits = b -> XCD b%8, same XCD as k_point for b)
// block 512 = 8 waves (wm 2 x wl 4); block tile: gate g's 128 ch x 128 L (lh); wave 64x32
__global__ __launch_bounds__(512, 2) void k_conv(
    const u16* __restrict__ Wpk, const u16* __restrict__ xT, const u16* __restrict__ hT,
    const float* __restrict__ cb, float* __restrict__ gates, float* __restrict__ stats, int t) {
  const int bid = blockIdx.x;
  const int b = bid & 31, lh = (bid >> 5) & 1, g = bid >> 6;
  const int L0 = lh << 7;
  const int tid = threadIdx.x, wave = tid >> 6, lane = tid & 63;
  const int wm = wave & 1, wl = wave >> 1;
  const int cgrp = (lane >> 4) << 4;
  const int l15 = lane & 15;

  __shared__ __align__(16) char ldsx[16896];   // 132 rows x 128 B (x, swizzled)
  __shared__ __align__(16) char ldsh[33792];   // 132 rows x 256 B (h, swizzled)
  __shared__ float red[8][2][2];

  float* gcur = gates + (b << 17);             // [b][512][256]

  // ---- stage x(t) and h(t) via global_load_lds (swizzle pre-baked in global) ----
  {
    const char* gx = (const char*)(xT + ((t << 5) + b) * 16896) + (lh << 14);
    for (int i = tid; i < 1056; i += 512) gl_lds16(gx + (i << 4), ldsx + (i << 4));
    const char* gh = (const char*)hT + b * 67584 + (lh << 15);
    for (int i = tid; i < 2112; i += 512) gl_lds16(gh + (i << 4), ldsh + (i << 4));
  }
  asm volatile("s_waitcnt vmcnt(0)" ::: "memory");
  __syncthreads();

  // ---- K-loop: 30 chunks, A direct from L1/L2, B from LDS, no barriers ----
  f32x4 zero4 = {0.f, 0.f, 0.f, 0.f};
  f32x4 acc[4][2];
  #pragma unroll
  for (int mi = 0; mi < 4; ++mi) { acc[mi][0] = zero4; acc[mi][1] = zero4; }

  const s16x8* Wv = (const s16x8*)Wpk;
  const int afb = (g << 3) + (wm << 2);
  for (int tap = 0; tap < 5; ++tap) {
    #pragma unroll
    for (int kk = 0; kk < 6; ++kk) {
      const int cc = tap * 6 + kk;
      s16x8 av[4], bv[2];
      #pragma unroll
      for (int mi = 0; mi < 4; ++mi)
        av[mi] = Wv[(((cc << 5) + afb + mi) << 6) + lane];
      #pragma unroll
      for (int ni = 0; ni < 2; ++ni) {
        const int row = (wl << 5) + (ni << 4) + l15 + tap;
        const int sw = (row & 7) << 4;
        bv[ni] = (kk < 2)
          ? *(const s16x8*)(ldsx + (row << 7) + (((kk << 6) + cgrp) ^ sw))
          : *(const s16x8*)(ldsh + (row << 8) + ((((kk - 2) << 6) + cgrp) ^ sw));
      }
      #pragma unroll
      for (int mi = 0; mi < 4; ++mi) {
        acc[mi][0] = __builtin_amdgcn_mfma_f32_16x16x32_bf16(av[mi], bv[0], acc[mi][0], 0, 0, 0);
        acc[mi][1] = __builtin_amdgcn_mfma_f32_16x16x32_bf16(av[mi], bv[1], acc[mi][1], 0, 0, 0);
      }
    }
  }

  // ---- epilogue: +bias, write f32 gates(t), per-group partial stats ----
  const int ch4 = (lane >> 4) << 2;
  float sum[2] = {0.f, 0.f}, sq[2] = {0.f, 0.f};
  #pragma unroll
  for (int mi = 0; mi < 4; ++mi) {
    const int gc0 = (g << 7) + (wm << 6) + (mi << 4) + ch4;
    const f32x4 bias = *(const f32x4*)(cb + gc0);
    const int gi = mi >> 1;
    #pragma unroll
    for (int ni = 0; ni < 2; ++ni) {
      const int l = L0 + (wl << 5) + (ni << 4) + l15;
      #pragma unroll
      for (int r = 0; r < 4; ++r) {
        float v = acc[mi][ni][r] + bias[r];
        gcur[((gc0 + r) << 8) + l] = v;
        sum[gi] += v; sq[gi] += v * v;
      }
    }
  }
  #pragma unroll
  for (int off = 1; off < 64; off <<= 1) {
    sum[0] += __shfl_xor(sum[0], off); sq[0] += __shfl_xor(sq[0], off);
    sum[1] += __shfl_xor(sum[1], off); sq[1] += __shfl_xor(sq[1], off);
  }
  if (lane == 0) {
    red[wave][0][0] = sum[0]; red[wave][0][1] = sq[0];
    red[wave][1][0] = sum[1]; red[wave][1][1] = sq[1];
  }
  __syncthreads();
  if (tid < 8) {   // fixed-order 4-wave sum -> deterministic, no atomics
    const int cs2 = tid >> 1, j = tid & 1;
    const int wm2 = cs2 >> 1, gi = cs2 & 1;   // group (g*4 + cs2) = channels g*128 + cs2*32 + [0,32)
    float v = red[wm2][gi][j] + red[wm2 + 2][gi][j] + red[wm2 + 4][gi][j] + red[wm2 + 6][gi][j];
    stats[(((b << 1) | lh) << 5) + (((g << 2) + cs2) << 1) + j] = v;
  }
}

// ---------- GN apply + LSTM pointwise + transposed swizzled h write (once per cell) ----------
// grid 256: bid = ((cs*2+lh)<<5) + b; block 256 thr, no LDS; l-major coalesced
__global__ __launch_bounds__(256) void k_point(
    const float* __restrict__ gates, const float* __restrict__ stats,
    const float* __restrict__ gnw, const float* __restrict__ gnb,
    float* __restrict__ cx, u16* __restrict__ hT, float* __restrict__ out, int t) {
  const int bid = blockIdx.x;
  const int b = bid & 31, lh = (bid >> 5) & 1, cs = bid >> 6;   // cs = 32-ch strip
  const int tid = threadIdx.x;

  const float inv = 1.0f / 8192.0f;
  float mu[4], rs[4];
  #pragma unroll
  for (int g = 0; g < 4; ++g) {
    const int grp = (g << 2) + cs;
    float s = stats[((b << 1) << 5) + (grp << 1)]     + stats[(((b << 1) | 1) << 5) + (grp << 1)];
    float q = stats[((b << 1) << 5) + (grp << 1) + 1] + stats[(((b << 1) | 1) << 5) + (grp << 1) + 1];
    float m = s * inv;
    mu[g] = m;
    rs[g] = rsqrtf(q * inv - m * m + EPS);
  }

  const int lr = tid & 127;
  const int l = (lh << 7) + lr;
  const int kq0 = tid >> 7;
  const float* gb_ = gates + (b << 17);   // [b][512][256]
  float* cxb_ = cx + (b << 15);           // [b][128][256], updated in place
  float* outp = out + (((t << 5) + b) << 15);

  #pragma unroll
  for (int k2 = 0; k2 < 2; ++k2) {
    const int kq = kq0 + (k2 << 1);       // octet within strip, 0..3
    const int c8 = (cs << 5) + (kq << 3);
    s16x8 hp;
    #pragma unroll
    for (int r = 0; r < 8; ++r) {
      const int c = c8 + r;
      const int ci = (c << 8) + l;
      float vi = gb_[ci];
      float vf = gb_[ci + (128 << 8)];
      float vg = gb_[ci + (256 << 8)];
      float vo = gb_[ci + (384 << 8)];
      vi = (vi - mu[0]) * rs[0] * gnw[c]       + gnb[c];
      vf = (vf - mu[1]) * rs[1] * gnw[c + 128] + gnb[c + 128];
      vg = (vg - mu[2]) * rs[2] * gnw[c + 256] + gnb[c + 256];
      vo = (vo - mu[3]) * rs[3] * gnw[c + 384] + gnb[c + 384];
      float cyv = sigm(vf) * cxb_[ci] + sigm(vi) * tanh_f(vg);
      float hyv = sigm(vo) * tanh_f(cyv);
      cxb_[ci] = cyv;
      outp[ci] = hyv;
      hp[r] = (short)f2bf(hyv);
      if (t == 31) {
        const int cxi = (b << 15) + ci;
        out[33554432 + cxi] = hyv;   // final hy
        out[34603008 + cxi] = cyv;   // final cy
      }
    }
    // one 16B granule store in hT's swizzled layout (row = l+2, granule = cs*4+kq)
    const int row = l + 2;
    char* dst = (char*)hT + b * 67584 + (row << 8) +
                ((((cs << 2) + kq) << 4) ^ ((row & 7) << 4));
    *(i32x4*)dst = *(const i32x4*)&hp;
  }
}

// ---------- launch ----------
extern "C" void kernel_launch(void* const* d_in, const int* in_sizes, int n_in,
                              void* d_out, int out_size, void* d_ws, size_t ws_size,
                              hipStream_t stream) {
  const float* x  = (const float*)d_in[0];
  const float* cw = (const float*)d_in[1];
  const float* cb = (const float*)d_in[2];
  const float* gw = (const float*)d_in[3];
  const float* gb = (const float*)d_in[4];
  float* out = (float*)d_out;
  char* ws = (char*)d_ws;

  u16*   Wpk   = (u16*)(ws);                 //     983,040 B
  u16*   xT    = (u16*)(ws + 983040);        //  34,603,008 B
  u16*   hT    = (u16*)(ws + 35586048);      //   2,162,688 B
  float* cx    = (float*)(ws + 37748736);    //   4,194,304 B
  float* gates = (float*)(ws + 41943040);    //  16,777,216 B
  float* stats = (float*)(ws + 58720256);    //       8,192 B  (~58.7 MB)

  k_wcvt<<<1920, 256, 0, stream>>>(cw, Wpk);
  k_xtrans<<<1024, 256, 0, stream>>>(x, xT);
  k_init<<<512, 256, 0, stream>>>((i32x4*)hT, (i32x4*)cx);
  for (int t = 0; t < 32; ++t) {
    k_conv<<<256, 512, 0, stream>>>(Wpk, xT, hT, cb, gates, stats, t);
    k_point<<<256, 256, 0, stream>>>(gates, stats, gw, gb, cx, hT, out, t);
  }
}

// Round 11
// 674.958 us; speedup vs baseline: 3.9556x; 1.3972x over previous
//
#include <hip/hip_runtime.h>

typedef unsigned short u16;
typedef unsigned int u32;
typedef unsigned long long u64;
typedef __attribute__((ext_vector_type(4))) float f32x4;
typedef __attribute__((ext_vector_type(8))) short s16x8;
typedef __attribute__((ext_vector_type(4))) int i32x4;

#define EPS 1e-5f

// ---------- helpers ----------
__device__ __forceinline__ u16 f2bf(float f) {
  unsigned u = __float_as_uint(f);
  return (u16)((u + 0x7fffu + ((u >> 16) & 1u)) >> 16);
}
__device__ __forceinline__ float sigm(float x) { return 1.0f / (1.0f + __expf(-x)); }
__device__ __forceinline__ float tanh_f(float x) {
  float e = __expf(-2.0f * fabsf(x));
  float r = (1.0f - e) / (1.0f + e);
  return copysignf(r, x);
}
__device__ __forceinline__ void gl_lds16(const void* g, void* l) {
  __builtin_amdgcn_global_load_lds(
      (const __attribute__((address_space(1))) u32*)g,
      (__attribute__((address_space(3))) u32*)l, 16, 0, 0);
}

// ---------- merged setup: weight pack + x transpose + zero ----------
// bid<1920: wcvt; 1920..2943: xtrans; 2944..3455: zero hT/cx/flags
__global__ __launch_bounds__(256) void k_setup(
    const float* __restrict__ cw, u16* __restrict__ Wpk,
    const float* __restrict__ x, u16* __restrict__ xT,
    i32x4* __restrict__ hTz, i32x4* __restrict__ cxz, i32x4* __restrict__ flz) {
  const int bid = blockIdx.x, tid = threadIdx.x;
  __shared__ __align__(16) u16 ltile[256 * 72];
  if (bid < 1920) {
    // f = (tap*6+kk)*32 + of ; of = gate-ch>>4 ; element = lane*8+j
    // A[o][c]: o = of*16 + (lane&15), c = kk*32 + (lane>>4)*8 + j
    int idx = bid * 256 + tid;                 // exactly 491520
    int f = idx >> 9, r = idx & 511;
    int lane = r >> 3, j = r & 7;
    int of = f & 31, tk = f >> 5;
    int kk = tk % 6, tap = tk / 6;
    int o = (of << 4) + (lane & 15);
    int c = (kk << 5) + ((lane >> 4) << 3) + j;
    Wpk[idx] = f2bf(cw[(o * 192 + c) * 5 + tap]);
  } else if (bid < 2944) {
    // x (t,b,64,256) f32 -> xT[t*32+b][264 rows][64 ch] bf16, swizzled, halos zeroed
    int tb = bid - 1920;
    const float* src = x + tb * (64 * 256);
    for (int it = 0; it < 64; ++it) {
      int idx = it * 256 + tid;
      int c = idx >> 8, l = idx & 255;
      ltile[l * 72 + c] = f2bf(src[idx]);
    }
    __syncthreads();
    char* dst = (char*)(xT + tb * 16896);
    i32x4 z = {0, 0, 0, 0};
    for (int i = tid; i < 2112; i += 256) {    // 264 rows x 8 chunks
      int r = i >> 3, ch = i & 7;
      i32x4 v = z;
      if (r >= 2 && r < 258) v = *(const i32x4*)(ltile + (r - 2) * 72 + ch * 8);
      *(i32x4*)(dst + r * 128 + ((ch * 16) ^ ((r & 7) << 4))) = v;
    }
  } else {
    int base = (bid - 2944) * 256 + tid;       // 131072 threads
    i32x4 z = {0, 0, 0, 0};
    for (int i = base; i < 270336; i += 131072) hTz[i] = z;   // hT both buffers
    for (int i = base; i < 262144; i += 131072) cxz[i] = z;   // cx
    for (int i = base; i < 2048;   i += 131072) flz[i] = z;   // 8192 flags
  }
}

// ---------- fused step: stage x/h -> conv -> bias+stats -> partner spin -> GN+LSTM -> h write ----------
// grid 256: bid = ((cs*2+lh)<<5) | b  (all same-b blocks + partner on same XCD: bid%8 = b%8)
// block 512 = 8 waves (wm 2 x wl 4). Block: ch strip cs (32 hy-ch x 4 gates = M128) x 128 L (lh).
// Wave: 4 m-frags (one per gate, same 16 ch) x 2 n-frags -> thread-local LSTM cells.
__global__ __launch_bounds__(512) void k_step(
    const u16* __restrict__ Wpk, const u16* __restrict__ xT, u16* __restrict__ hT,
    const float* __restrict__ cb, const float* __restrict__ gnw, const float* __restrict__ gnb,
    float* __restrict__ cx, float* __restrict__ out,
    float* __restrict__ stats, int* __restrict__ flags, int t) {
  const int bid = blockIdx.x;
  const int b = bid & 31, lh = (bid >> 5) & 1, cs = bid >> 6;
  const int L0 = lh << 7;
  const int tid = threadIdx.x, wave = tid >> 6, lane = tid & 63;
  const int wm = wave & 1, wl = wave >> 1;
  const int l15 = lane & 15, q = lane >> 4;
  const int cgrp = q << 4;

  __shared__ __align__(16) char ldsx[16896];   // 132 rows x 128 B (x, swizzled)
  __shared__ __align__(16) char ldsh[33792];   // 132 rows x 256 B (h, swizzled)
  __shared__ __align__(16) char hl[8192];      // 128 l x 64 B (32 ch bf16, 8B-slot swizzled)
  __shared__ float red[8][4][2];
  __shared__ float blkstat[8];
  __shared__ float smu[4], srs[4];

  const u16* hTr = hT + (t & 1) * 1081344;
  u16* hTw = hT + ((t + 1) & 1) * 1081344;

  // ---- stage x(t), h(t) (swizzle pre-baked in global) ----
  {
    const char* gx = (const char*)(xT + ((t << 5) + b) * 16896) + (lh << 14);
    for (int i = tid; i < 1056; i += 512) gl_lds16(gx + (i << 4), ldsx + (i << 4));
    const char* gh = (const char*)hTr + b * 67584 + (lh << 15);
    for (int i = tid; i < 2112; i += 512) gl_lds16(gh + (i << 4), ldsh + (i << 4));
  }
  asm volatile("s_waitcnt vmcnt(0)" ::: "memory");
  __syncthreads();

  // ---- K-loop: 30 chunks, A direct from L1/L2, B from LDS, no barriers ----
  f32x4 zero4 = {0.f, 0.f, 0.f, 0.f};
  f32x4 acc[4][2];
  #pragma unroll
  for (int g = 0; g < 4; ++g) { acc[g][0] = zero4; acc[g][1] = zero4; }

  const s16x8* Wv = (const s16x8*)Wpk;
  for (int tap = 0; tap < 5; ++tap) {
    #pragma unroll
    for (int kk = 0; kk < 6; ++kk) {
      const int cc = tap * 6 + kk;
      s16x8 av[4], bv[2];
      #pragma unroll
      for (int g = 0; g < 4; ++g) {
        const int of = (g << 3) + (cs << 1) + wm;
        av[g] = Wv[(((cc << 5) + of) << 6) + lane];
      }
      #pragma unroll
      for (int ni = 0; ni < 2; ++ni) {
        const int rr = (wl << 5) + (ni << 4) + l15 + tap;
        const int sw = (rr & 7) << 4;
        bv[ni] = (kk < 2)
          ? *(const s16x8*)(ldsx + (rr << 7) + (((kk << 6) + cgrp) ^ sw))
          : *(const s16x8*)(ldsh + (rr << 8) + ((((kk - 2) << 6) + cgrp) ^ sw));
      }
      #pragma unroll
      for (int g = 0; g < 4; ++g) {
        acc[g][0] = __builtin_amdgcn_mfma_f32_16x16x32_bf16(av[g], bv[0], acc[g][0], 0, 0, 0);
        acc[g][1] = __builtin_amdgcn_mfma_f32_16x16x32_bf16(av[g], bv[1], acc[g][1], 0, 0, 0);
      }
    }
  }

  // ---- +bias, per-gate partial stats (strip cs x this 128L) ----
  const int chq = (cs << 5) + (wm << 4) + (q << 2);   // hy-ch base for r=0
  float sum4[4], sq4[4];
  #pragma unroll
  for (int g = 0; g < 4; ++g) {
    const f32x4 bias = *(const f32x4*)(cb + (g << 7) + chq);
    sum4[g] = 0.f; sq4[g] = 0.f;
    #pragma unroll
    for (int ni = 0; ni < 2; ++ni)
      #pragma unroll
      for (int r = 0; r < 4; ++r) {
        float v = acc[g][ni][r] + bias[r];
        acc[g][ni][r] = v;
        sum4[g] += v; sq4[g] += v * v;
      }
  }
  // preload pointwise params + cx (hides L2 latency under reduce+spin)
  f32x4 w4[4], b4[4];
  float cxv[2][4];
  #pragma unroll
  for (int g = 0; g < 4; ++g) {
    w4[g] = *(const f32x4*)(gnw + (g << 7) + chq);
    b4[g] = *(const f32x4*)(gnb + (g << 7) + chq);
  }
  #pragma unroll
  for (int ni = 0; ni < 2; ++ni) {
    const int l = L0 + (wl << 5) + (ni << 4) + l15;
    #pragma unroll
    for (int r = 0; r < 4; ++r)
      cxv[ni][r] = cx[(b << 15) + ((chq + r) << 8) + l];
  }
  #pragma unroll
  for (int off = 1; off < 64; off <<= 1) {
    #pragma unroll
    for (int g = 0; g < 4; ++g) {
      sum4[g] += __shfl_xor(sum4[g], off);
      sq4[g]  += __shfl_xor(sq4[g], off);
    }
  }
  if (lane == 0) {
    #pragma unroll
    for (int g = 0; g < 4; ++g) { red[wave][g][0] = sum4[g]; red[wave][g][1] = sq4[g]; }
  }
  __syncthreads();
  if (tid < 8) {
    const int g = tid >> 1, j = tid & 1;
    float v = 0.f;
    #pragma unroll
    for (int w = 0; w < 8; ++w) v += red[w][g][j];
    blkstat[tid] = v;
  }
  __syncthreads();

  // ---- partner spin (lh^1): 32B stats exchange; fresh slot per t; fixed-order sum ----
  const int sidx = (((t << 5) + b) << 3) + (cs << 1) + lh;
  if (tid == 0) {
    float* sp = stats + (sidx << 3);
    #pragma unroll
    for (int j = 0; j < 8; ++j)
      __hip_atomic_store(sp + j, blkstat[j], __ATOMIC_RELAXED, __HIP_MEMORY_SCOPE_AGENT);
    __hip_atomic_store(&flags[sidx], 1, __ATOMIC_RELEASE, __HIP_MEMORY_SCOPE_AGENT);
    while (__hip_atomic_load(&flags[sidx ^ 1], __ATOMIC_RELAXED, __HIP_MEMORY_SCOPE_AGENT) == 0)
      __builtin_amdgcn_s_sleep(2);
    __builtin_amdgcn_fence(__ATOMIC_ACQUIRE, "agent");
    const float* pe = stats + ((sidx & ~1) << 3);   // even lh first -> identical in both partners
    const float* po = stats + ((sidx | 1) << 3);
    const float inv = 1.0f / 8192.0f;
    #pragma unroll
    for (int g = 0; g < 4; ++g) {
      float s = __hip_atomic_load(pe + (g << 1), __ATOMIC_RELAXED, __HIP_MEMORY_SCOPE_AGENT)
              + __hip_atomic_load(po + (g << 1), __ATOMIC_RELAXED, __HIP_MEMORY_SCOPE_AGENT);
      float qv = __hip_atomic_load(pe + (g << 1) + 1, __ATOMIC_RELAXED, __HIP_MEMORY_SCOPE_AGENT)
               + __hip_atomic_load(po + (g << 1) + 1, __ATOMIC_RELAXED, __HIP_MEMORY_SCOPE_AGENT);
      float m = s * inv;
      smu[g] = m;
      srs[g] = rsqrtf(qv * inv - m * m + EPS);
    }
  }
  __syncthreads();

  // ---- GN apply + LSTM pointwise (thread-local, all 4 gates in registers) ----
  const float mu0 = smu[0], mu1 = smu[1], mu2 = smu[2], mu3 = smu[3];
  const float rs0 = srs[0], rs1 = srs[1], rs2 = srs[2], rs3 = srs[3];
  float* outp = out + (((t << 5) + b) << 15);
  #pragma unroll
  for (int ni = 0; ni < 2; ++ni) {
    const int l = L0 + (wl << 5) + (ni << 4) + l15;
    const int ll = l - L0;
    u16 hp[4];
    #pragma unroll
    for (int r = 0; r < 4; ++r) {
      const int c = chq + r;
      float vi = (acc[0][ni][r] - mu0) * rs0 * w4[0][r] + b4[0][r];
      float vf = (acc[1][ni][r] - mu1) * rs1 * w4[1][r] + b4[1][r];
      float vg = (acc[2][ni][r] - mu2) * rs2 * w4[2][r] + b4[2][r];
      float vo = (acc[3][ni][r] - mu3) * rs3 * w4[3][r] + b4[3][r];
      float cyv = sigm(vf) * cxv[ni][r] + sigm(vi) * tanh_f(vg);
      float hyv = sigm(vo) * tanh_f(cyv);
      const int ci = (c << 8) + l;
      cx[(b << 15) + ci] = cyv;
      outp[ci] = hyv;
      hp[r] = f2bf(hyv);
      if (t == 31) {
        out[33554432 + (b << 15) + ci] = hyv;   // final hy
        out[34603008 + (b << 15) + ci] = cyv;   // final cy
      }
    }
    // 8B slot store, slot-swizzled by (ll&3) so granule reads are spread
    *(u64*)(hl + (ll << 6) + (((wm << 5) + (q << 3)) ^ ((ll & 3) << 4))) =
        *(const u64*)hp;
  }
  __syncthreads();

  // ---- cooperative transposed h write: strip cs, this 128 L -> hTw ----
  {
    const int ll = tid >> 2, k = tid & 3;
    const int row = L0 + ll + 2;
    i32x4 v = *(const i32x4*)(hl + (ll << 6) + ((k << 4) ^ ((ll & 3) << 4)));
    char* dst = (char*)hTw + b * 67584 + (row << 8) +
                ((((cs << 2) + k) << 4) ^ ((row & 7) << 4));
    *(i32x4*)dst = v;
  }
}

// ---------- launch ----------
extern "C" void kernel_launch(void* const* d_in, const int* in_sizes, int n_in,
                              void* d_out, int out_size, void* d_ws, size_t ws_size,
                              hipStream_t stream) {
  const float* x  = (const float*)d_in[0];
  const float* cw = (const float*)d_in[1];
  const float* cb = (const float*)d_in[2];
  const float* gw = (const float*)d_in[3];
  const float* gb = (const float*)d_in[4];
  float* out = (float*)d_out;
  char* ws = (char*)d_ws;

  u16*   Wpk   = (u16*)(ws);                 //     983,040 B
  u16*   xT    = (u16*)(ws + 983040);        //  34,603,008 B
  u16*   hT    = (u16*)(ws + 35586048);      //   4,325,376 B (ping-pong)
  float* cx    = (float*)(ws + 39911424);    //   4,194,304 B
  float* stats = (float*)(ws + 44105728);    //     262,144 B
  int*   flags = (int*)(ws + 44367872);      //      32,768 B  (~44.4 MB)

  k_setup<<<3456, 256, 0, stream>>>(cw, Wpk, x, xT, (i32x4*)hT, (i32x4*)cx, (i32x4*)flags);
  for (int t = 0; t < 32; ++t)
    k_step<<<256, 512, 0, stream>>>(Wpk, xT, hT, cb, gw, gb, cx, out, stats, flags, t);
}